// Round 1
// baseline (222.587 us; speedup 1.0000x reference)
//
#include <hip/hip_runtime.h>
#include <stdint.h>

#define SEQ 8192
#define CTX 2048
#define DK  128

typedef __attribute__((ext_vector_type(8))) __bf16 bf16x8;
typedef __attribute__((ext_vector_type(4))) float f32x4;
typedef unsigned short u16;

__device__ __forceinline__ u16 f2bf(float f) {            // RNE
  unsigned int u = __builtin_bit_cast(unsigned int, f);
  u += 0x7FFFu + ((u >> 16) & 1u);
  return (u16)(u >> 16);
}
__device__ __forceinline__ u16 f2bf_fast(float f) {       // round-half-up (P only)
  unsigned int u = __builtin_bit_cast(unsigned int, f);
  return (u16)((u + 0x8000u) >> 16);
}
__device__ __forceinline__ float bf2f(u16 h) {
  unsigned int u = ((unsigned int)h) << 16;
  return __builtin_bit_cast(float, u);
}
__device__ __forceinline__ void gl_lds16(const void* g, void* l) {
  __builtin_amdgcn_global_load_lds((__attribute__((address_space(1))) void*)g,
                                   (__attribute__((address_space(3))) void*)l, 16, 0, 0);
}
__device__ __forceinline__ f32x4 mfma16(bf16x8 a, bf16x8 b, f32x4 c) {
  return __builtin_amdgcn_mfma_f32_16x16x32_bf16(a, b, c, 0, 0, 0);
}

// ---------------- x -> bf16 ----------------
__global__ __launch_bounds__(256) void k_cvt_x(const float* __restrict__ x, u16* __restrict__ xb) {
  int i = blockIdx.x * 256 + threadIdx.x;        // 4 elems each, grid 16384
  float4 a = ((const float4*)x)[i];
  ushort4 r;
  r.x = f2bf(a.x); r.y = f2bf(a.y); r.z = f2bf(a.z); r.w = f2bf(a.w);
  ((ushort4*)xb)[i] = r;
}

// ---------------- W -> Wt (bf16, [n][k]); Wq prescaled by sqrt(dk) ----------------
__global__ __launch_bounds__(256) void k_cvt_w(const float* __restrict__ wq, const float* __restrict__ wk,
                                               const float* __restrict__ wv, u16* __restrict__ wT) {
  int mat = blockIdx.y;
  const float* w = mat == 0 ? wq : (mat == 1 ? wk : wv);
  float scale = (mat == 0) ? 11.313708498984761f : 1.0f;  // sqrt(128)
  int tk = blockIdx.x & 63, tn = blockIdx.x >> 6;         // grid.x = 256
  __shared__ float t[32][33];
  int tx = threadIdx.x & 31, ty = threadIdx.x >> 5;
  int k0 = tk * 32, n0 = tn * 32;
#pragma unroll
  for (int j = 0; j < 4; j++) {
    int kk = ty + j * 8;
    t[kk][tx] = w[(size_t)(k0 + kk) * DK + n0 + tx] * scale;
  }
  __syncthreads();
  u16* o = wT + (size_t)mat * DK * CTX;
#pragma unroll
  for (int j = 0; j < 4; j++) {
    int nn = ty + j * 8;
    o[(size_t)(n0 + nn) * CTX + k0 + tx] = f2bf(t[tx][nn]);
  }
}

// ---------------- QKV GEMM: C[8192][128] = xb @ wT(mat) ----------------
__global__ __launch_bounds__(256, 2) void k_qkv(const u16* __restrict__ xb, const u16* __restrict__ wT,
                                                u16* __restrict__ qb, u16* __restrict__ kb, u16* __restrict__ vb) {
  __shared__ __align__(16) u16 As[128 * 32];
  __shared__ __align__(16) u16 Bs[128 * 32];
  int bid = blockIdx.x;                  // 192 blocks
  int xcd = bid & 7, j = bid >> 3;       // same A-strip triple -> same XCD (bid%8)
  int mat = j % 3, mb = xcd * 8 + j / 3; // mb 0..63
  const u16* B = wT + (size_t)mat * DK * CTX;
  u16* C = mat == 0 ? qb : (mat == 1 ? kb : vb);
  int tid = threadIdx.x, lane = tid & 63, w = tid >> 6;
  int r15 = lane & 15, gq = lane >> 4;
  int wr = w >> 1, wc = w & 1;
  f32x4 acc[4][4] = {};
  for (int k0 = 0; k0 < CTX; k0 += 32) {
    __syncthreads();
#pragma unroll
    for (int i = 0; i < 2; i++) {
      int c = i * 256 + tid; int row = c >> 2, cc = c & 3;
      gl_lds16(xb + (size_t)(mb * 128 + row) * CTX + k0 + cc * 8, &As[(i * 256 + w * 64) * 8]);
    }
#pragma unroll
    for (int i = 0; i < 2; i++) {
      int c = i * 256 + tid; int row = c >> 2, cc = c & 3;
      gl_lds16(B + (size_t)row * CTX + k0 + cc * 8, &Bs[(i * 256 + w * 64) * 8]);
    }
    asm volatile("s_waitcnt vmcnt(0)" ::: "memory");
    __syncthreads();
    bf16x8 af[4], bfr[4];
#pragma unroll
    for (int mi = 0; mi < 4; mi++) af[mi] = *(const bf16x8*)&As[(wr * 64 + mi * 16 + r15) * 32 + gq * 8];
#pragma unroll
    for (int ni = 0; ni < 4; ni++) bfr[ni] = *(const bf16x8*)&Bs[(wc * 64 + ni * 16 + r15) * 32 + gq * 8];
#pragma unroll
    for (int mi = 0; mi < 4; mi++)
#pragma unroll
      for (int ni = 0; ni < 4; ni++)
        acc[mi][ni] = mfma16(af[mi], bfr[ni], acc[mi][ni]);
  }
#pragma unroll
  for (int mi = 0; mi < 4; mi++)
#pragma unroll
    for (int ni = 0; ni < 4; ni++)
#pragma unroll
      for (int rr = 0; rr < 4; rr++) {
        int mrow = mb * 128 + wr * 64 + mi * 16 + gq * 4 + rr;
        int ncol = wc * 64 + ni * 16 + r15;
        C[(size_t)mrow * DK + ncol] = f2bf(acc[mi][ni][rr]);
      }
}

// ---------------- P2: column stats (max, sumexp) over s, per t ----------------
// grid 512: ss = bid&7 (s-split, == XCD), tb = bid>>3 (t-block of 128)
__global__ __launch_bounds__(256, 2) void k_p2(const u16* __restrict__ qb, const u16* __restrict__ kb,
                                               float* __restrict__ m_part, float* __restrict__ z_part) {
  __shared__ __align__(16) u16 Ks2[4 * 128 * 32];  // [kd][t128][32]
  __shared__ __align__(16) u16 Qs2[4 * 64 * 32];   // [kd][s64][32]
  const float L2E = 1.4426950408889634f;
  int bid = blockIdx.x;
  int ss = bid & 7, tb = bid >> 3;
  int t0 = tb * 128, s0 = ss * 1024;
  int tid = threadIdx.x, lane = tid & 63, w = tid >> 6;
  int r15 = lane & 15, gq = lane >> 4;
#pragma unroll
  for (int i = 0; i < 8; i++) {
    int c = i * 256 + tid; int kd = c >> 9, row = (c >> 2) & 127, cc = c & 3;
    gl_lds16(kb + (size_t)(t0 + row) * DK + kd * 32 + cc * 8, &Ks2[(i * 256 + w * 64) * 8]);
  }
  asm volatile("s_waitcnt vmcnt(0)" ::: "memory");
  __syncthreads();
  bf16x8 af[2][4];
#pragma unroll
  for (int mi = 0; mi < 2; mi++)
#pragma unroll
    for (int kd = 0; kd < 4; kd++)
      af[mi][kd] = *(const bf16x8*)&Ks2[kd * 4096 + (w * 32 + mi * 16 + r15) * 32 + gq * 8];
  float runM[8], runZ[8];
#pragma unroll
  for (int jj = 0; jj < 8; jj++) { runM[jj] = -3.0e38f; runZ[jj] = 0.f; }

  for (int sc = 0; sc < 1024; sc += 64) {
#pragma unroll
    for (int i = 0; i < 4; i++) {
      int c = i * 256 + tid; int kd = c >> 8, row = (c >> 2) & 63, cc = c & 3;
      gl_lds16(qb + (size_t)(s0 + sc + row) * DK + kd * 32 + cc * 8, &Qs2[(i * 256 + w * 64) * 8]);
    }
    asm volatile("s_waitcnt vmcnt(0)" ::: "memory");
    __syncthreads();
    f32x4 pacc[4][2] = {};
#pragma unroll
    for (int ni = 0; ni < 4; ni++)
#pragma unroll
      for (int kd = 0; kd < 4; kd++) {
        bf16x8 bq = *(const bf16x8*)&Qs2[kd * 2048 + (ni * 16 + r15) * 32 + gq * 8];
        pacc[ni][0] = mfma16(af[0][kd], bq, pacc[ni][0]);
        pacc[ni][1] = mfma16(af[1][kd], bq, pacc[ni][1]);
      }
    __syncthreads();   // Qs2 readers done before next restage
#pragma unroll
    for (int mi = 0; mi < 2; mi++)
#pragma unroll
      for (int rr = 0; rr < 4; rr++) {
        int jj = mi * 4 + rr;
        float m8 = fmaxf(fmaxf(pacc[0][mi][rr], pacc[1][mi][rr]),
                         fmaxf(pacc[2][mi][rr], pacc[3][mi][rr])) * L2E;
        if (m8 > runM[jj] - 60.f) {
          float nm = fmaxf(runM[jj], m8);
          float z = runZ[jj] * __builtin_amdgcn_exp2f(runM[jj] - nm);
#pragma unroll
          for (int ni = 0; ni < 4; ni++)
            z += __builtin_amdgcn_exp2f(fmaf(pacc[ni][mi][rr], L2E, -nm));
          runZ[jj] = z; runM[jj] = nm;
        }
      }
  }
  // butterfly over the 16 lanes sharing each t-row (bits 0..3 of lane)
#pragma unroll
  for (int d = 1; d < 16; d <<= 1) {
#pragma unroll
    for (int jj = 0; jj < 8; jj++) {
      float oM = __shfl_xor(runM[jj], d);
      float oZ = __shfl_xor(runZ[jj], d);
      float nm = fmaxf(runM[jj], oM);
      runZ[jj] = runZ[jj] * __builtin_amdgcn_exp2f(runM[jj] - nm) + oZ * __builtin_amdgcn_exp2f(oM - nm);
      runM[jj] = nm;
    }
  }
  if (r15 == 0) {
#pragma unroll
    for (int mi = 0; mi < 2; mi++)
#pragma unroll
      for (int rr = 0; rr < 4; rr++) {
        int t = t0 + w * 32 + mi * 16 + gq * 4 + rr;
        m_part[ss * SEQ + t] = runM[mi * 4 + rr];
        z_part[ss * SEQ + t] = runZ[mi * 4 + rr];
      }
  }
}

// ---------------- P2c: combine partials; mL[t]; vT[d][t] = v[t][d]/Z_t ----------------
__global__ __launch_bounds__(256) void k_p2c(const float* __restrict__ m_part, const float* __restrict__ z_part,
                                             const u16* __restrict__ vb, float* __restrict__ mL,
                                             u16* __restrict__ vT) {
  int t0 = blockIdx.x * 64;   // grid 128
  int tid = threadIdx.x;
  __shared__ float rz[64];
  __shared__ __align__(16) u16 vt[64 * DK];
  if (tid < 64) {
    int t = t0 + tid;
    float m0 = -3.0e38f, z = 0.f;
#pragma unroll
    for (int p = 0; p < 8; p++) {
      float a = m_part[p * SEQ + t], b = z_part[p * SEQ + t];
      float nm = fmaxf(m0, a);
      z = z * __builtin_amdgcn_exp2f(m0 - nm) + b * __builtin_amdgcn_exp2f(a - nm);
      m0 = nm;
    }
    mL[t] = m0;
    rz[tid] = 1.0f / z;
  }
  const uint4* vs = (const uint4*)(vb + (size_t)t0 * DK);
  uint4* vd = (uint4*)vt;
#pragma unroll
  for (int i = 0; i < 4; i++) vd[i * 256 + tid] = vs[i * 256 + tid];
  __syncthreads();
  int d = tid >> 1, half = tid & 1;
#pragma unroll
  for (int jj = 0; jj < 32; jj++) {
    int tl = half * 32 + jj;
    float f = bf2f(vt[tl * DK + d]) * rz[tl];
    vT[(size_t)d * SEQ + t0 + tl] = f2bf(f);
  }
}

// ---------------- P3: out_part = exp2(QK^T*L - mL) @ vT ----------------
// grid 512: ts = bid&7 (t-split, == XCD), sb = bid>>3
__global__ __launch_bounds__(256, 2) void k_p3(const u16* __restrict__ qb, const u16* __restrict__ kb,
                                               const u16* __restrict__ vT, const float* __restrict__ mLg,
                                               float* __restrict__ outp) {
  __shared__ __align__(16) u16 Ks2[4 * 64 * 32];   // [kd][t64][32]
  __shared__ __align__(16) u16 Vs2[2 * 128 * 32];  // [kt][d128][32]
  __shared__ __align__(16) u16 Ps[2 * 128 * 40];   // [kt][s128][40] (pad->16B-aligned b128)
  __shared__ __align__(16) float mLs[1024];
  const float L2E = 1.4426950408889634f;
  int bid = blockIdx.x;
  int ts = bid & 7, sb = bid >> 3;
  int s0 = sb * 128, tbase = ts * 1024;
  int tid = threadIdx.x, lane = tid & 63, w = tid >> 6;
  int r15 = lane & 15, gq = lane >> 4;
  int wr = w >> 1, wc = w & 1;
  gl_lds16(mLg + tbase + tid * 4, &mLs[w * 256]);
  bf16x8 qf[2][4];                                  // wave's q strip, loop-invariant
#pragma unroll
  for (int ni = 0; ni < 2; ni++)
#pragma unroll
    for (int kd = 0; kd < 4; kd++)
      qf[ni][kd] = *(const bf16x8*)(qb + (size_t)(s0 + w * 32 + ni * 16 + r15) * DK + kd * 32 + gq * 8);
  f32x4 o[4][4] = {};
  for (int tc = 0; tc < 1024; tc += 64) {
    __syncthreads();
#pragma unroll
    for (int i = 0; i < 4; i++) {
      int c = i * 256 + tid; int kd = c >> 8, t = (c >> 2) & 63, cc = c & 3;
      gl_lds16(kb + (size_t)(tbase + tc + t) * DK + kd * 32 + cc * 8, &Ks2[(i * 256 + w * 64) * 8]);
    }
#pragma unroll
    for (int i = 0; i < 4; i++) {
      int c = i * 256 + tid; int kt = c >> 9, d = (c >> 2) & 127, cc = c & 3;
      gl_lds16(vT + (size_t)d * SEQ + tbase + tc + kt * 32 + cc * 8, &Vs2[(i * 256 + w * 64) * 8]);
    }
    asm volatile("s_waitcnt vmcnt(0)" ::: "memory");
    __syncthreads();
    // QK (swapped: P^T[t][s]) + exp + pack to Ps
#pragma unroll
    for (int mi = 0; mi < 4; mi++) {
      bf16x8 a4[4];
#pragma unroll
      for (int kd = 0; kd < 4; kd++)
        a4[kd] = *(const bf16x8*)&Ks2[kd * 2048 + (mi * 16 + r15) * 32 + gq * 8];
      f32x4 p0 = {}, p1 = {};
#pragma unroll
      for (int kd = 0; kd < 4; kd++) {
        p0 = mfma16(a4[kd], qf[0][kd], p0);
        p1 = mfma16(a4[kd], qf[1][kd], p1);
      }
      ushort4 pk0, pk1;
      {
        float e;
        float mv0 = mLs[tc + mi * 16 + gq * 4 + 0];
        float mv1 = mLs[tc + mi * 16 + gq * 4 + 1];
        float mv2 = mLs[tc + mi * 16 + gq * 4 + 2];
        float mv3 = mLs[tc + mi * 16 + gq * 4 + 3];
        e = __builtin_amdgcn_exp2f(fmaf(p0[0], L2E, -mv0)); pk0.x = f2bf_fast(e);
        e = __builtin_amdgcn_exp2f(fmaf(p0[1], L2E, -mv1)); pk0.y = f2bf_fast(e);
        e = __builtin_amdgcn_exp2f(fmaf(p0[2], L2E, -mv2)); pk0.z = f2bf_fast(e);
        e = __builtin_amdgcn_exp2f(fmaf(p0[3], L2E, -mv3)); pk0.w = f2bf_fast(e);
        e = __builtin_amdgcn_exp2f(fmaf(p1[0], L2E, -mv0)); pk1.x = f2bf_fast(e);
        e = __builtin_amdgcn_exp2f(fmaf(p1[1], L2E, -mv1)); pk1.y = f2bf_fast(e);
        e = __builtin_amdgcn_exp2f(fmaf(p1[2], L2E, -mv2)); pk1.z = f2bf_fast(e);
        e = __builtin_amdgcn_exp2f(fmaf(p1[3], L2E, -mv3)); pk1.w = f2bf_fast(e);
      }
      int ktp = mi >> 1;
      int w32 = (mi & 1) * 16 + gq * 4;
      *(ushort4*)&Ps[ktp * 5120 + (w * 32 + r15) * 40 + w32] = pk0;
      *(ushort4*)&Ps[ktp * 5120 + (w * 32 + 16 + r15) * 40 + w32] = pk1;
    }
    __syncthreads();
    // PV
#pragma unroll
    for (int kt = 0; kt < 2; kt++) {
      bf16x8 pa[4], vv[4];
#pragma unroll
      for (int mi2 = 0; mi2 < 4; mi2++)
        pa[mi2] = *(const bf16x8*)&Ps[kt * 5120 + (wr * 64 + mi2 * 16 + r15) * 40 + gq * 8];
#pragma unroll
      for (int ni2 = 0; ni2 < 4; ni2++)
        vv[ni2] = *(const bf16x8*)&Vs2[kt * 4096 + (wc * 64 + ni2 * 16 + r15) * 32 + gq * 8];
#pragma unroll
      for (int mi2 = 0; mi2 < 4; mi2++)
#pragma unroll
        for (int ni2 = 0; ni2 < 4; ni2++)
          o[mi2][ni2] = mfma16(pa[mi2], vv[ni2], o[mi2][ni2]);
    }
  }
  float* dst = outp + (size_t)ts * SEQ * DK;
#pragma unroll
  for (int mi2 = 0; mi2 < 4; mi2++)
#pragma unroll
    for (int ni2 = 0; ni2 < 4; ni2++)
#pragma unroll
      for (int rr = 0; rr < 4; rr++) {
        int srow = s0 + wr * 64 + mi2 * 16 + gq * 4 + rr;
        int dcol = wc * 64 + ni2 * 16 + r15;
        dst[(size_t)srow * DK + dcol] = o[mi2][ni2][rr];
      }
}

// ---------------- P4: reduce 8 t-split partials ----------------
__global__ __launch_bounds__(256) void k_p4(const float* __restrict__ outp, float* __restrict__ out) {
  int i = blockIdx.x * 256 + threadIdx.x;   // grid 1024, float4 each
  const float4* s = (const float4*)outp;
  float4 a = s[i];
#pragma unroll
  for (int p = 1; p < 8; p++) {
    float4 b = s[(size_t)p * 262144 + i];
    a.x += b.x; a.y += b.y; a.z += b.z; a.w += b.w;
  }
  ((float4*)out)[i] = a;
}

extern "C" void kernel_launch(void* const* d_in, const int* in_sizes, int n_in,
                              void* d_out, int out_size, void* d_ws, size_t ws_size,
                              hipStream_t stream) {
  (void)in_sizes; (void)n_in; (void)out_size; (void)ws_size;
  const float* x  = (const float*)d_in[0];
  const float* wq = (const float*)d_in[1];
  const float* wk = (const float*)d_in[2];
  const float* wv = (const float*)d_in[3];
  float* out = (float*)d_out;

  char* wsb = (char*)d_ws;
  u16*   xb    = (u16*)wsb;                       // 32 MB (dead after k_qkv)
  float* outp  = (float*)wsb;                     // 32 MB, overlaid on xb
  u16*   wT    = (u16*)(wsb + 33554432);          // 1.5 MB
  u16*   qb    = (u16*)(wsb + 35127296);          // 2 MB (prescaled by sqrt(dk))
  u16*   kb    = (u16*)(wsb + 37224448);          // 2 MB
  u16*   vb    = (u16*)(wsb + 39321600);          // 2 MB
  u16*   vT    = (u16*)(wsb + 41418752);          // 2 MB  (v/Z, transposed [d][t])
  float* mLf   = (float*)(wsb + 43515904);        // 32 KB (max in log2-space)
  float* mpart = (float*)(wsb + 43548672);        // 256 KB
  float* zpart = (float*)(wsb + 43810816);        // 256 KB -> end 44,072,960 B

  k_cvt_x<<<16384, 256, 0, stream>>>(x, xb);
  k_cvt_w<<<dim3(256, 3), 256, 0, stream>>>(wq, wk, wv, wT);
  k_qkv<<<192, 256, 0, stream>>>(xb, wT, qb, kb, vb);
  k_p2<<<512, 256, 0, stream>>>(qb, kb, mpart, zpart);
  k_p2c<<<128, 256, 0, stream>>>(mpart, zpart, vb, mLf, vT);
  k_p3<<<512, 256, 0, stream>>>(qb, kb, vT, mLf, outp);
  k_p4<<<1024, 256, 0, stream>>>(outp, out);
}

// Round 2
// 217.145 us; speedup vs baseline: 1.0251x; 1.0251x over previous
//
#include <hip/hip_runtime.h>
#include <stdint.h>

#define SEQ 8192
#define CTX 2048
#define DK  128

typedef __attribute__((ext_vector_type(8))) __bf16 bf16x8;
typedef __attribute__((ext_vector_type(4))) float f32x4;
typedef unsigned short u16;

__device__ __forceinline__ u16 f2bf(float f) {            // RNE
  unsigned int u = __builtin_bit_cast(unsigned int, f);
  u += 0x7FFFu + ((u >> 16) & 1u);
  return (u16)(u >> 16);
}
__device__ __forceinline__ u16 f2bf_fast(float f) {       // round-half-up (P only)
  unsigned int u = __builtin_bit_cast(unsigned int, f);
  return (u16)((u + 0x8000u) >> 16);
}
__device__ __forceinline__ float bf2f(u16 h) {
  unsigned int u = ((unsigned int)h) << 16;
  return __builtin_bit_cast(float, u);
}
__device__ __forceinline__ void gl_lds16(const void* g, void* l) {
  __builtin_amdgcn_global_load_lds((__attribute__((address_space(1))) void*)g,
                                   (__attribute__((address_space(3))) void*)l, 16, 0, 0);
}
__device__ __forceinline__ f32x4 mfma16(bf16x8 a, bf16x8 b, f32x4 c) {
  return __builtin_amdgcn_mfma_f32_16x16x32_bf16(a, b, c, 0, 0, 0);
}

// ---------------- x -> bf16 ----------------
__global__ __launch_bounds__(256) void k_cvt_x(const float* __restrict__ x, u16* __restrict__ xb) {
  int i = blockIdx.x * 256 + threadIdx.x;        // 4 elems each, grid 16384
  float4 a = ((const float4*)x)[i];
  ushort4 r;
  r.x = f2bf(a.x); r.y = f2bf(a.y); r.z = f2bf(a.z); r.w = f2bf(a.w);
  ((ushort4*)xb)[i] = r;
}

// ---------------- W -> Wt (bf16, [n][k]); Wq prescaled by sqrt(dk) ----------------
__global__ __launch_bounds__(256) void k_cvt_w(const float* __restrict__ wq, const float* __restrict__ wk,
                                               const float* __restrict__ wv, u16* __restrict__ wT) {
  int mat = blockIdx.y;
  const float* w = mat == 0 ? wq : (mat == 1 ? wk : wv);
  float scale = (mat == 0) ? 11.313708498984761f : 1.0f;  // sqrt(128)
  int tk = blockIdx.x & 63, tn = blockIdx.x >> 6;         // grid.x = 256
  __shared__ float t[32][33];
  int tx = threadIdx.x & 31, ty = threadIdx.x >> 5;
  int k0 = tk * 32, n0 = tn * 32;
#pragma unroll
  for (int j = 0; j < 4; j++) {
    int kk = ty + j * 8;
    t[kk][tx] = w[(size_t)(k0 + kk) * DK + n0 + tx] * scale;
  }
  __syncthreads();
  u16* o = wT + (size_t)mat * DK * CTX;
#pragma unroll
  for (int j = 0; j < 4; j++) {
    int nn = ty + j * 8;
    o[(size_t)(n0 + nn) * CTX + k0 + tx] = f2bf(t[tx][nn]);
  }
}

// ---------------- QKV GEMM: C[8192][128] = xb @ wT(mat), BK=64, dbuf ----------------
__global__ __launch_bounds__(256, 2) void k_qkv(const u16* __restrict__ xb, const u16* __restrict__ wT,
                                                u16* __restrict__ qb, u16* __restrict__ kb, u16* __restrict__ vb) {
  __shared__ __align__(16) u16 As[2][8192];   // [buf][kd2][row128][32]
  __shared__ __align__(16) u16 Bs[2][8192];
  int bid = blockIdx.x;                  // 192 blocks
  int xcd = bid & 7, j = bid >> 3;       // same A-strip triple -> same XCD
  int mat = j % 3, mb = xcd * 8 + j / 3; // mb 0..63
  const u16* B = wT + (size_t)mat * DK * CTX;
  u16* C = mat == 0 ? qb : (mat == 1 ? kb : vb);
  int tid = threadIdx.x, lane = tid & 63, w = tid >> 6;
  int r15 = lane & 15, gq = lane >> 4;
  int wr = w >> 1, wc = w & 1;
  int gqx = gq ^ ((r15 >> 1) & 3);       // bank-swizzled read col-group

  auto stage = [&](int buf, int k0) {
#pragma unroll
    for (int i = 0; i < 4; i++) {
      int c = i * 256 + tid;
      int kd = c >> 9, row = (c >> 2) & 127, cc = (c & 3) ^ ((c >> 3) & 3);
      gl_lds16(xb + (size_t)(mb * 128 + row) * CTX + k0 + kd * 32 + cc * 8, &As[buf][(i * 256 + w * 64) * 8]);
    }
#pragma unroll
    for (int i = 0; i < 4; i++) {
      int c = i * 256 + tid;
      int kd = c >> 9, row = (c >> 2) & 127, cc = (c & 3) ^ ((c >> 3) & 3);
      gl_lds16(B + (size_t)row * CTX + k0 + kd * 32 + cc * 8, &Bs[buf][(i * 256 + w * 64) * 8]);
    }
  };

  f32x4 acc[4][4] = {};
  stage(0, 0);
  asm volatile("s_waitcnt vmcnt(0)" ::: "memory");
  __syncthreads();
  for (int it = 0; it < 32; ++it) {
    int buf = it & 1;
    if (it < 31) stage(buf ^ 1, it * 64 + 64);
    bf16x8 af[2][4], bfr[2][4];
#pragma unroll
    for (int kd = 0; kd < 2; kd++)
#pragma unroll
      for (int mi = 0; mi < 4; mi++)
        af[kd][mi] = *(const bf16x8*)&As[buf][kd * 4096 + (wr * 64 + mi * 16 + r15) * 32 + gqx * 8];
#pragma unroll
    for (int kd = 0; kd < 2; kd++)
#pragma unroll
      for (int ni = 0; ni < 4; ni++)
        bfr[kd][ni] = *(const bf16x8*)&Bs[buf][kd * 4096 + (wc * 64 + ni * 16 + r15) * 32 + gqx * 8];
#pragma unroll
    for (int mi = 0; mi < 4; mi++)
#pragma unroll
      for (int ni = 0; ni < 4; ni++) {
        acc[mi][ni] = mfma16(af[0][mi], bfr[0][ni], acc[mi][ni]);
        acc[mi][ni] = mfma16(af[1][mi], bfr[1][ni], acc[mi][ni]);
      }
    asm volatile("s_waitcnt vmcnt(0)" ::: "memory");
    __syncthreads();
  }
#pragma unroll
  for (int mi = 0; mi < 4; mi++)
#pragma unroll
    for (int ni = 0; ni < 4; ni++)
#pragma unroll
      for (int rr = 0; rr < 4; rr++) {
        int mrow = mb * 128 + wr * 64 + mi * 16 + gq * 4 + rr;
        int ncol = wc * 64 + ni * 16 + r15;
        C[(size_t)mrow * DK + ncol] = f2bf(acc[mi][ni][rr]);
      }
}

// ---------------- P2: column stats (max, sumexp) over s, per t ----------------
// grid 512: ss = bid&7 (s-split, == XCD), tb = bid>>3 (t-block of 128)
__global__ __launch_bounds__(256, 2) void k_p2(const u16* __restrict__ qb, const u16* __restrict__ kb,
                                               float* __restrict__ m_part, float* __restrict__ z_part) {
  __shared__ __align__(16) u16 Ks2[16384];     // [kd4][t128][32] 32KB
  __shared__ __align__(16) u16 Qs2[2][8192];   // [buf][kd4][s64][32] 16KB each
  const float L2E = 1.4426950408889634f;
  int bid = blockIdx.x;
  int ss = bid & 7, tb = bid >> 3;
  int t0 = tb * 128, s0 = ss * 1024;
  int tid = threadIdx.x, lane = tid & 63, w = tid >> 6;
  int r15 = lane & 15, gq = lane >> 4;
  int gqx = gq ^ ((r15 >> 1) & 3);

  auto stageQ = [&](int buf, int sc) {
#pragma unroll
    for (int i = 0; i < 4; i++) {
      int c = i * 256 + tid;
      int kd = c >> 8, row = (c >> 2) & 63, cc = (c & 3) ^ ((c >> 3) & 3);
      gl_lds16(qb + (size_t)(s0 + sc + row) * DK + kd * 32 + cc * 8, &Qs2[buf][(i * 256 + w * 64) * 8]);
    }
  };

#pragma unroll
  for (int i = 0; i < 8; i++) {
    int c = i * 256 + tid;
    int kd = c >> 9, row = (c >> 2) & 127, cc = (c & 3) ^ ((c >> 3) & 3);
    gl_lds16(kb + (size_t)(t0 + row) * DK + kd * 32 + cc * 8, &Ks2[(i * 256 + w * 64) * 8]);
  }
  stageQ(0, 0);
  asm volatile("s_waitcnt vmcnt(0)" ::: "memory");
  __syncthreads();
  bf16x8 af[2][4];
#pragma unroll
  for (int mi = 0; mi < 2; mi++)
#pragma unroll
    for (int kd = 0; kd < 4; kd++)
      af[mi][kd] = *(const bf16x8*)&Ks2[kd * 4096 + (w * 32 + mi * 16 + r15) * 32 + gqx * 8];
  float runM[8], runZ[8];
#pragma unroll
  for (int jj = 0; jj < 8; jj++) { runM[jj] = -3.0e38f; runZ[jj] = 0.f; }

  for (int sc = 0; sc < 1024; sc += 64) {
    int buf = (sc >> 6) & 1;
    if (sc < 960) stageQ(buf ^ 1, sc + 64);
    f32x4 pacc[4][2] = {};
#pragma unroll
    for (int ni = 0; ni < 4; ni++)
#pragma unroll
      for (int kd = 0; kd < 4; kd++) {
        bf16x8 bq = *(const bf16x8*)&Qs2[buf][kd * 2048 + (ni * 16 + r15) * 32 + gqx * 8];
        pacc[ni][0] = mfma16(af[0][kd], bq, pacc[ni][0]);
        pacc[ni][1] = mfma16(af[1][kd], bq, pacc[ni][1]);
      }
#pragma unroll
    for (int mi = 0; mi < 2; mi++)
#pragma unroll
      for (int rr = 0; rr < 4; rr++) {
        int jj = mi * 4 + rr;
        float m8 = fmaxf(fmaxf(pacc[0][mi][rr], pacc[1][mi][rr]),
                         fmaxf(pacc[2][mi][rr], pacc[3][mi][rr])) * L2E;
        if (m8 > runM[jj] - 60.f) {
          float nm = fmaxf(runM[jj], m8);
          float z = runZ[jj] * __builtin_amdgcn_exp2f(runM[jj] - nm);
#pragma unroll
          for (int ni = 0; ni < 4; ni++)
            z += __builtin_amdgcn_exp2f(fmaf(pacc[ni][mi][rr], L2E, -nm));
          runZ[jj] = z; runM[jj] = nm;
        }
      }
    asm volatile("s_waitcnt vmcnt(0)" ::: "memory");
    __syncthreads();
  }
  // butterfly over the 16 lanes sharing each t-row
#pragma unroll
  for (int d = 1; d < 16; d <<= 1) {
#pragma unroll
    for (int jj = 0; jj < 8; jj++) {
      float oM = __shfl_xor(runM[jj], d);
      float oZ = __shfl_xor(runZ[jj], d);
      float nm = fmaxf(runM[jj], oM);
      runZ[jj] = runZ[jj] * __builtin_amdgcn_exp2f(runM[jj] - nm) + oZ * __builtin_amdgcn_exp2f(oM - nm);
      runM[jj] = nm;
    }
  }
  if (r15 == 0) {
#pragma unroll
    for (int mi = 0; mi < 2; mi++)
#pragma unroll
      for (int rr = 0; rr < 4; rr++) {
        int t = t0 + w * 32 + mi * 16 + gq * 4 + rr;
        m_part[ss * SEQ + t] = runM[mi * 4 + rr];
        z_part[ss * SEQ + t] = runZ[mi * 4 + rr];
      }
  }
}

// ---------------- P2c: combine partials; mL[t]; vT[d][t] = v[t][d]/Z_t ----------------
__global__ __launch_bounds__(256) void k_p2c(const float* __restrict__ m_part, const float* __restrict__ z_part,
                                             const u16* __restrict__ vb, float* __restrict__ mL,
                                             u16* __restrict__ vT) {
  int t0 = blockIdx.x * 64;   // grid 128
  int tid = threadIdx.x;
  __shared__ float rz[64];
  __shared__ __align__(16) u16 vt[64 * DK];
  if (tid < 64) {
    int t = t0 + tid;
    float m0 = -3.0e38f, z = 0.f;
#pragma unroll
    for (int p = 0; p < 8; p++) {
      float a = m_part[p * SEQ + t], b = z_part[p * SEQ + t];
      float nm = fmaxf(m0, a);
      z = z * __builtin_amdgcn_exp2f(m0 - nm) + b * __builtin_amdgcn_exp2f(a - nm);
      m0 = nm;
    }
    mL[t] = m0;
    rz[tid] = 1.0f / z;
  }
  const uint4* vs = (const uint4*)(vb + (size_t)t0 * DK);
  uint4* vd = (uint4*)vt;
#pragma unroll
  for (int i = 0; i < 4; i++) vd[i * 256 + tid] = vs[i * 256 + tid];
  __syncthreads();
  int d = tid >> 1, half = tid & 1;
#pragma unroll
  for (int jj = 0; jj < 32; jj++) {
    int tl = half * 32 + jj;
    float f = bf2f(vt[tl * DK + d]) * rz[tl];
    vT[(size_t)d * SEQ + t0 + tl] = f2bf(f);
  }
}

// ---------------- P3: out_part = exp2(QK^T*L - mL) @ vT ----------------
// grid 512: ts = bid&7 (t-split, == XCD), sb = bid>>3
__global__ __launch_bounds__(256, 2) void k_p3(const u16* __restrict__ qb, const u16* __restrict__ kb,
                                               const u16* __restrict__ vT, const float* __restrict__ mLg,
                                               float* __restrict__ outp) {
  __shared__ __align__(16) u16 Ks2[8192];       // [kd4][t64][32] 16KB (restaged during PV)
  __shared__ __align__(16) u16 Vs2[2][8192];    // dbuf [kt2][d128][32] 16KB each
  __shared__ __align__(16) u16 Ps[2 * 128 * 40];// [kt][s128][40] 20KB
  const float L2E = 1.4426950408889634f;
  int bid = blockIdx.x;
  int ts = bid & 7, sb = bid >> 3;
  int s0 = sb * 128, tbase = ts * 1024;
  int tid = threadIdx.x, lane = tid & 63, w = tid >> 6;
  int r15 = lane & 15, gq = lane >> 4;
  int wr = w >> 1, wc = w & 1;
  int gqx = gq ^ ((r15 >> 1) & 3);

  auto stageK = [&](int tc) {
#pragma unroll
    for (int i = 0; i < 4; i++) {
      int c = i * 256 + tid;
      int kd = c >> 8, t = (c >> 2) & 63, cc = (c & 3) ^ ((c >> 3) & 3);
      gl_lds16(kb + (size_t)(tbase + tc + t) * DK + kd * 32 + cc * 8, &Ks2[(i * 256 + w * 64) * 8]);
    }
  };
  auto stageV = [&](int buf, int tc) {
#pragma unroll
    for (int i = 0; i < 4; i++) {
      int c = i * 256 + tid;
      int kt = c >> 9, d = (c >> 2) & 127, cc = (c & 3) ^ ((c >> 3) & 3);
      gl_lds16(vT + (size_t)d * SEQ + tbase + tc + kt * 32 + cc * 8, &Vs2[buf][(i * 256 + w * 64) * 8]);
    }
  };

  bf16x8 qf[2][4];                                  // wave's q strip, loop-invariant
#pragma unroll
  for (int ni = 0; ni < 2; ni++)
#pragma unroll
    for (int kd = 0; kd < 4; kd++)
      qf[ni][kd] = *(const bf16x8*)(qb + (size_t)(s0 + w * 32 + ni * 16 + r15) * DK + kd * 32 + gq * 8);

  stageK(0);
  stageV(0, 0);
  asm volatile("s_waitcnt vmcnt(0)" ::: "memory");
  __syncthreads();

  f32x4 o[4][4] = {};
  for (int tc = 0; tc < 1024; tc += 64) {
    int vbuf = (tc >> 6) & 1;
    // prefetch mL window for this chunk (L2-resident)
    float4 mv4[4];
#pragma unroll
    for (int mi = 0; mi < 4; mi++)
      mv4[mi] = *(const float4*)(mLg + tbase + tc + mi * 16 + gq * 4);
    // QK (swapped: P^T[t][s]) + exp + pack to Ps
#pragma unroll
    for (int mi = 0; mi < 4; mi++) {
      bf16x8 a4[4];
#pragma unroll
      for (int kd = 0; kd < 4; kd++)
        a4[kd] = *(const bf16x8*)&Ks2[kd * 2048 + (mi * 16 + r15) * 32 + gqx * 8];
      f32x4 p0 = {}, p1 = {};
#pragma unroll
      for (int kd = 0; kd < 4; kd++) {
        p0 = mfma16(a4[kd], qf[0][kd], p0);
        p1 = mfma16(a4[kd], qf[1][kd], p1);
      }
      ushort4 pk0, pk1;
      {
        float e;
        float mv0 = mv4[mi].x, mv1 = mv4[mi].y, mv2 = mv4[mi].z, mv3 = mv4[mi].w;
        e = __builtin_amdgcn_exp2f(fmaf(p0[0], L2E, -mv0)); pk0.x = f2bf_fast(e);
        e = __builtin_amdgcn_exp2f(fmaf(p0[1], L2E, -mv1)); pk0.y = f2bf_fast(e);
        e = __builtin_amdgcn_exp2f(fmaf(p0[2], L2E, -mv2)); pk0.z = f2bf_fast(e);
        e = __builtin_amdgcn_exp2f(fmaf(p0[3], L2E, -mv3)); pk0.w = f2bf_fast(e);
        e = __builtin_amdgcn_exp2f(fmaf(p1[0], L2E, -mv0)); pk1.x = f2bf_fast(e);
        e = __builtin_amdgcn_exp2f(fmaf(p1[1], L2E, -mv1)); pk1.y = f2bf_fast(e);
        e = __builtin_amdgcn_exp2f(fmaf(p1[2], L2E, -mv2)); pk1.z = f2bf_fast(e);
        e = __builtin_amdgcn_exp2f(fmaf(p1[3], L2E, -mv3)); pk1.w = f2bf_fast(e);
      }
      int ktp = mi >> 1;
      int w32 = (mi & 1) * 16 + gq * 4;
      *(ushort4*)&Ps[ktp * 5120 + (w * 32 + r15) * 40 + w32] = pk0;
      *(ushort4*)&Ps[ktp * 5120 + (w * 32 + 16 + r15) * 40 + w32] = pk1;
    }
    __syncthreads();   // B1: QK done -> Ks2 dead, Ps ready
    if (tc < 960) {    // stage next K/V; latency hides under PV
      stageK(tc + 64);
      stageV(vbuf ^ 1, tc + 64);
    }
    // PV
#pragma unroll
    for (int kt = 0; kt < 2; kt++) {
      bf16x8 pa[4], vv[4];
#pragma unroll
      for (int mi2 = 0; mi2 < 4; mi2++)
        pa[mi2] = *(const bf16x8*)&Ps[kt * 5120 + (wr * 64 + mi2 * 16 + r15) * 40 + gq * 8];
#pragma unroll
      for (int ni2 = 0; ni2 < 4; ni2++)
        vv[ni2] = *(const bf16x8*)&Vs2[vbuf][kt * 4096 + (wc * 64 + ni2 * 16 + r15) * 32 + gqx * 8];
#pragma unroll
      for (int mi2 = 0; mi2 < 4; mi2++)
#pragma unroll
        for (int ni2 = 0; ni2 < 4; ni2++)
          o[mi2][ni2] = mfma16(pa[mi2], vv[ni2], o[mi2][ni2]);
    }
    asm volatile("s_waitcnt vmcnt(0)" ::: "memory");
    __syncthreads();   // B2: PV done, next K/V landed
  }
  float* dst = outp + (size_t)ts * SEQ * DK;
#pragma unroll
  for (int mi2 = 0; mi2 < 4; mi2++)
#pragma unroll
    for (int ni2 = 0; ni2 < 4; ni2++)
#pragma unroll
      for (int rr = 0; rr < 4; rr++) {
        int srow = s0 + wr * 64 + mi2 * 16 + gq * 4 + rr;
        int dcol = wc * 64 + ni2 * 16 + r15;
        dst[(size_t)srow * DK + dcol] = o[mi2][ni2][rr];
      }
}

// ---------------- P4: reduce 8 t-split partials ----------------
__global__ __launch_bounds__(256) void k_p4(const float* __restrict__ outp, float* __restrict__ out) {
  int i = blockIdx.x * 256 + threadIdx.x;   // grid 1024, float4 each
  const float4* s = (const float4*)outp;
  float4 a = s[i];
#pragma unroll
  for (int p = 1; p < 8; p++) {
    float4 b = s[(size_t)p * 262144 + i];
    a.x += b.x; a.y += b.y; a.z += b.z; a.w += b.w;
  }
  ((float4*)out)[i] = a;
}

extern "C" void kernel_launch(void* const* d_in, const int* in_sizes, int n_in,
                              void* d_out, int out_size, void* d_ws, size_t ws_size,
                              hipStream_t stream) {
  (void)in_sizes; (void)n_in; (void)out_size; (void)ws_size;
  const float* x  = (const float*)d_in[0];
  const float* wq = (const float*)d_in[1];
  const float* wk = (const float*)d_in[2];
  const float* wv = (const float*)d_in[3];
  float* out = (float*)d_out;

  char* wsb = (char*)d_ws;
  u16*   xb    = (u16*)wsb;                       // 32 MB (dead after k_qkv)
  float* outp  = (float*)wsb;                     // 32 MB, overlaid on xb
  u16*   wT    = (u16*)(wsb + 33554432);          // 1.5 MB
  u16*   qb    = (u16*)(wsb + 35127296);          // 2 MB (prescaled by sqrt(dk))
  u16*   kb    = (u16*)(wsb + 37224448);          // 2 MB
  u16*   vb    = (u16*)(wsb + 39321600);          // 2 MB
  u16*   vT    = (u16*)(wsb + 41418752);          // 2 MB  (v/Z, transposed [d][t])
  float* mLf   = (float*)(wsb + 43515904);        // 32 KB (max in log2-space)
  float* mpart = (float*)(wsb + 43548672);        // 256 KB
  float* zpart = (float*)(wsb + 43810816);        // 256 KB

  k_cvt_x<<<16384, 256, 0, stream>>>(x, xb);
  k_cvt_w<<<dim3(256, 3), 256, 0, stream>>>(wq, wk, wv, wT);
  k_qkv<<<192, 256, 0, stream>>>(xb, wT, qb, kb, vb);
  k_p2<<<512, 256, 0, stream>>>(qb, kb, mpart, zpart);
  k_p2c<<<128, 256, 0, stream>>>(mpart, zpart, vb, mLf, vT);
  k_p3<<<512, 256, 0, stream>>>(qb, kb, vT, mLf, outp);
  k_p4<<<1024, 256, 0, stream>>>(outp, out);
}

// Round 4
// 214.601 us; speedup vs baseline: 1.0372x; 1.0119x over previous
//
#include <hip/hip_runtime.h>
#include <stdint.h>

#define SEQ 8192
#define CTX 2048
#define DK  128

typedef __attribute__((ext_vector_type(8))) __bf16 bf16x8;
typedef __attribute__((ext_vector_type(4))) float f32x4;
typedef unsigned short u16;

__device__ __forceinline__ u16 f2bf(float f) {            // RNE
  unsigned int u = __builtin_bit_cast(unsigned int, f);
  u += 0x7FFFu + ((u >> 16) & 1u);
  return (u16)(u >> 16);
}
__device__ __forceinline__ u16 f2bf_fast(float f) {       // round-half-up (P only)
  unsigned int u = __builtin_bit_cast(unsigned int, f);
  return (u16)((u + 0x8000u) >> 16);
}
__device__ __forceinline__ float bf2f(u16 h) {
  unsigned int u = ((unsigned int)h) << 16;
  return __builtin_bit_cast(float, u);
}
__device__ __forceinline__ void gl_lds16(const void* g, void* l) {
  __builtin_amdgcn_global_load_lds((__attribute__((address_space(1))) void*)g,
                                   (__attribute__((address_space(3))) void*)l, 16, 0, 0);
}
__device__ __forceinline__ f32x4 mfma16(bf16x8 a, bf16x8 b, f32x4 c) {
  return __builtin_amdgcn_mfma_f32_16x16x32_bf16(a, b, c, 0, 0, 0);
}

// ---------------- W -> Wt (bf16, [n][k]); Wq prescaled by sqrt(dk) ----------------
__global__ __launch_bounds__(256) void k_cvt_w(const float* __restrict__ wq, const float* __restrict__ wk,
                                               const float* __restrict__ wv, u16* __restrict__ wT) {
  int mat = blockIdx.y;
  const float* w = mat == 0 ? wq : (mat == 1 ? wk : wv);
  float scale = (mat == 0) ? 11.313708498984761f : 1.0f;  // sqrt(128)
  int tk = blockIdx.x & 63, tn = blockIdx.x >> 6;         // grid.x = 256
  __shared__ float t[32][33];
  int tx = threadIdx.x & 31, ty = threadIdx.x >> 5;
  int k0 = tk * 32, n0 = tn * 32;
#pragma unroll
  for (int j = 0; j < 4; j++) {
    int kk = ty + j * 8;
    t[kk][tx] = w[(size_t)(k0 + kk) * DK + n0 + tx] * scale;
  }
  __syncthreads();
  u16* o = wT + (size_t)mat * DK * CTX;
#pragma unroll
  for (int j = 0; j < 4; j++) {
    int nn = ty + j * 8;
    o[(size_t)(n0 + nn) * CTX + k0 + tx] = f2bf(t[tx][nn]);
  }
}

// ---------------- QKV GEMM (fused x->bf16): C[8192][128] = bf16(x) @ wT(mat) ----------------
// M-tile 64, grid 384: xcd-major layout
__global__ __launch_bounds__(256, 3) void k_qkv(const float* __restrict__ x, const u16* __restrict__ wT,
                                                u16* __restrict__ qb, u16* __restrict__ kb, u16* __restrict__ vb) {
  __shared__ __align__(16) u16 As[2][4096];   // [buf][kd2][row64][32] 8KB each
  __shared__ __align__(16) u16 Bs[2][8192];   // [buf][kd2][row128][32] 16KB each
  int bid = blockIdx.x;                  // 384 blocks
  int sid = (bid & 7) * 48 + (bid >> 3); // contiguous strip per XCD
  int mat = sid >> 7, mb = sid & 127;    // mat 0..2, mb 0..127
  const u16* B = wT + (size_t)mat * DK * CTX;
  u16* C = mat == 0 ? qb : (mat == 1 ? kb : vb);
  int tid = threadIdx.x, lane = tid & 63, w = tid >> 6;
  int r15 = lane & 15, gq = lane >> 4;
  int wr = w & 1, wc = w >> 1;
  int gqx = gq ^ ((r15 >> 1) & 3);       // bank-swizzled read col-group
  int arow = tid >> 2, af4 = tid & 3;

  auto stageB = [&](int buf, int k0) {
#pragma unroll
    for (int i = 0; i < 4; i++) {
      int c = i * 256 + tid;
      int kd = c >> 9, row = (c >> 2) & 127, cc = (c & 3) ^ ((c >> 3) & 3);
      gl_lds16(B + (size_t)row * CTX + k0 + kd * 32 + cc * 8, &Bs[buf][(i * 256 + w * 64) * 8]);
    }
  };
  auto loadA = [&](int k0, float4* ar) {
#pragma unroll
    for (int rr = 0; rr < 4; rr++) {
      int f4 = af4 + rr * 4;
      ar[rr] = *(const float4*)(x + (size_t)(mb * 64 + arow) * CTX + k0 + f4 * 4);
    }
  };
  auto writeA = [&](int buf, const float4* ar) {
#pragma unroll
    for (int rr = 0; rr < 4; rr++) {
      int f4 = af4 + rr * 4;
      int kd = f4 >> 3, g8 = (f4 >> 1) & 3, inner = (f4 & 1) * 4;
      int g8x = g8 ^ ((arow >> 1) & 3);
      ushort4 v;
      v.x = f2bf(ar[rr].x); v.y = f2bf(ar[rr].y); v.z = f2bf(ar[rr].z); v.w = f2bf(ar[rr].w);
      *(ushort4*)&As[buf][kd * 2048 + arow * 32 + g8x * 8 + inner] = v;
    }
  };

  f32x4 acc[2][4] = {};
  float4 ar[4];
  stageB(0, 0);
  loadA(0, ar);
  writeA(0, ar);
  asm volatile("s_waitcnt vmcnt(0)" ::: "memory");
  __syncthreads();
  for (int it = 0; it < 32; ++it) {
    int buf = it & 1;
    if (it < 31) {
      stageB(buf ^ 1, it * 64 + 64);
      loadA(it * 64 + 64, ar);
    }
    bf16x8 af[2][2], bfr[2][4];
#pragma unroll
    for (int kd = 0; kd < 2; kd++)
#pragma unroll
      for (int mi = 0; mi < 2; mi++)
        af[kd][mi] = *(const bf16x8*)&As[buf][kd * 2048 + (wr * 32 + mi * 16 + r15) * 32 + gqx * 8];
#pragma unroll
    for (int kd = 0; kd < 2; kd++)
#pragma unroll
      for (int ni = 0; ni < 4; ni++)
        bfr[kd][ni] = *(const bf16x8*)&Bs[buf][kd * 4096 + (wc * 64 + ni * 16 + r15) * 32 + gqx * 8];
#pragma unroll
    for (int mi = 0; mi < 2; mi++)
#pragma unroll
      for (int ni = 0; ni < 4; ni++) {
        acc[mi][ni] = mfma16(af[0][mi], bfr[0][ni], acc[mi][ni]);
        acc[mi][ni] = mfma16(af[1][mi], bfr[1][ni], acc[mi][ni]);
      }
    if (it < 31) writeA(buf ^ 1, ar);
    asm volatile("s_waitcnt vmcnt(0)" ::: "memory");
    __syncthreads();
  }
#pragma unroll
  for (int mi = 0; mi < 2; mi++)
#pragma unroll
    for (int ni = 0; ni < 4; ni++)
#pragma unroll
      for (int rr = 0; rr < 4; rr++) {
        int mrow = mb * 64 + wr * 32 + mi * 16 + gq * 4 + rr;
        int ncol = wc * 64 + ni * 16 + r15;
        C[(size_t)mrow * DK + ncol] = f2bf(acc[mi][ni][rr]);
      }
}

// ---------------- P2: column stats (max, sumexp) over s, per t ----------------
// grid 512: ss = bid&7 (s-split, == XCD), tb = bid>>3 (t-block of 128)
__global__ __launch_bounds__(256, 2) void k_p2(const u16* __restrict__ qb, const u16* __restrict__ kb,
                                               float* __restrict__ m_part, float* __restrict__ z_part) {
  __shared__ __align__(16) u16 Ks2[16384];     // [kd4][t128][32] 32KB
  __shared__ __align__(16) u16 Qs2[2][8192];   // [buf][kd4][s64][32] 16KB each
  const float L2E = 1.4426950408889634f;
  int bid = blockIdx.x;
  int ss = bid & 7, tb = bid >> 3;
  int t0 = tb * 128, s0 = ss * 1024;
  int tid = threadIdx.x, lane = tid & 63, w = tid >> 6;
  int r15 = lane & 15, gq = lane >> 4;
  int gqx = gq ^ ((r15 >> 1) & 3);

  auto stageQ = [&](int buf, int sc) {
#pragma unroll
    for (int i = 0; i < 4; i++) {
      int c = i * 256 + tid;
      int kd = c >> 8, row = (c >> 2) & 63, cc = (c & 3) ^ ((c >> 3) & 3);
      gl_lds16(qb + (size_t)(s0 + sc + row) * DK + kd * 32 + cc * 8, &Qs2[buf][(i * 256 + w * 64) * 8]);
    }
  };

#pragma unroll
  for (int i = 0; i < 8; i++) {
    int c = i * 256 + tid;
    int kd = c >> 9, row = (c >> 2) & 127, cc = (c & 3) ^ ((c >> 3) & 3);
    gl_lds16(kb + (size_t)(t0 + row) * DK + kd * 32 + cc * 8, &Ks2[(i * 256 + w * 64) * 8]);
  }
  stageQ(0, 0);
  asm volatile("s_waitcnt vmcnt(0)" ::: "memory");
  __syncthreads();
  bf16x8 af[2][4];
#pragma unroll
  for (int mi = 0; mi < 2; mi++)
#pragma unroll
    for (int kd = 0; kd < 4; kd++)
      af[mi][kd] = *(const bf16x8*)&Ks2[kd * 4096 + (w * 32 + mi * 16 + r15) * 32 + gqx * 8];
  float runM[8], runZ[8];
#pragma unroll
  for (int jj = 0; jj < 8; jj++) { runM[jj] = -3.0e38f; runZ[jj] = 0.f; }

  for (int sc = 0; sc < 1024; sc += 64) {
    int buf = (sc >> 6) & 1;
    if (sc < 960) stageQ(buf ^ 1, sc + 64);
    f32x4 pacc[4][2] = {};
#pragma unroll
    for (int ni = 0; ni < 4; ni++)
#pragma unroll
      for (int kd = 0; kd < 4; kd++) {
        bf16x8 bq = *(const bf16x8*)&Qs2[buf][kd * 2048 + (ni * 16 + r15) * 32 + gqx * 8];
        pacc[ni][0] = mfma16(af[0][kd], bq, pacc[ni][0]);
        pacc[ni][1] = mfma16(af[1][kd], bq, pacc[ni][1]);
      }
#pragma unroll
    for (int mi = 0; mi < 2; mi++)
#pragma unroll
      for (int rr = 0; rr < 4; rr++) {
        int jj = mi * 4 + rr;
        float m8 = fmaxf(fmaxf(pacc[0][mi][rr], pacc[1][mi][rr]),
                         fmaxf(pacc[2][mi][rr], pacc[3][mi][rr])) * L2E;
        if (m8 > runM[jj] - 60.f) {
          float nm = fmaxf(runM[jj], m8);
          float z = runZ[jj] * __builtin_amdgcn_exp2f(runM[jj] - nm);
#pragma unroll
          for (int ni = 0; ni < 4; ni++)
            z += __builtin_amdgcn_exp2f(fmaf(pacc[ni][mi][rr], L2E, -nm));
          runZ[jj] = z; runM[jj] = nm;
        }
      }
    asm volatile("s_waitcnt vmcnt(0)" ::: "memory");
    __syncthreads();
  }
#pragma unroll
  for (int d = 1; d < 16; d <<= 1) {
#pragma unroll
    for (int jj = 0; jj < 8; jj++) {
      float oM = __shfl_xor(runM[jj], d);
      float oZ = __shfl_xor(runZ[jj], d);
      float nm = fmaxf(runM[jj], oM);
      runZ[jj] = runZ[jj] * __builtin_amdgcn_exp2f(runM[jj] - nm) + oZ * __builtin_amdgcn_exp2f(oM - nm);
      runM[jj] = nm;
    }
  }
  if (r15 == 0) {
#pragma unroll
    for (int mi = 0; mi < 2; mi++)
#pragma unroll
      for (int rr = 0; rr < 4; rr++) {
        int t = t0 + w * 32 + mi * 16 + gq * 4 + rr;
        m_part[ss * SEQ + t] = runM[mi * 4 + rr];
        z_part[ss * SEQ + t] = runZ[mi * 4 + rr];
      }
  }
}

// ---------------- P2c: combine partials; mL[t]; vT[d][t] = v[t][d]/Z_t ----------------
__global__ __launch_bounds__(256) void k_p2c(const float* __restrict__ m_part, const float* __restrict__ z_part,
                                             const u16* __restrict__ vb, float* __restrict__ mL,
                                             u16* __restrict__ vT) {
  int t0 = blockIdx.x * 64;   // grid 128
  int tid = threadIdx.x;
  __shared__ float rz[64];
  __shared__ __align__(16) u16 vt[64 * DK];
  if (tid < 64) {
    int t = t0 + tid;
    float m0 = -3.0e38f, z = 0.f;
#pragma unroll
    for (int p = 0; p < 8; p++) {
      float a = m_part[p * SEQ + t], b = z_part[p * SEQ + t];
      float nm = fmaxf(m0, a);
      z = z * __builtin_amdgcn_exp2f(m0 - nm) + b * __builtin_amdgcn_exp2f(a - nm);
      m0 = nm;
    }
    mL[t] = m0;
    rz[tid] = 1.0f / z;
  }
  const uint4* vs = (const uint4*)(vb + (size_t)t0 * DK);
  uint4* vd = (uint4*)vt;
#pragma unroll
  for (int i = 0; i < 4; i++) vd[i * 256 + tid] = vs[i * 256 + tid];
  __syncthreads();
  int d = tid >> 1, half = tid & 1;
#pragma unroll
  for (int jj = 0; jj < 32; jj++) {
    int tl = half * 32 + jj;
    float f = bf2f(vt[tl * DK + d]) * rz[tl];
    vT[(size_t)d * SEQ + t0 + tl] = f2bf(f);
  }
}

// ---------------- P3: out_part = exp2(QK^T*L - mL) @ vT ----------------
// grid 512: ts = bid&7 (t-split, == XCD), sb = bid>>3
__global__ __launch_bounds__(256, 2) void k_p3(const u16* __restrict__ qb, const u16* __restrict__ kb,
                                               const u16* __restrict__ vT, const float* __restrict__ mLg,
                                               float* __restrict__ outp) {
  __shared__ __align__(16) u16 Ks2[8192];       // [kd4][t64][32] 16KB (restaged during PV)
  __shared__ __align__(16) u16 Vs2[2][8192];    // dbuf [kt2][d128][32] 16KB each
  __shared__ __align__(16) u16 Ps[2 * 128 * 40];// [kt][s128][40] 20KB
  const float L2E = 1.4426950408889634f;
  int bid = blockIdx.x;
  int ts = bid & 7, sb = bid >> 3;
  int s0 = sb * 128, tbase = ts * 1024;
  int tid = threadIdx.x, lane = tid & 63, w = tid >> 6;
  int r15 = lane & 15, gq = lane >> 4;
  int wr = w >> 1, wc = w & 1;
  int gqx = gq ^ ((r15 >> 1) & 3);

  auto stageK = [&](int tc) {
#pragma unroll
    for (int i = 0; i < 4; i++) {
      int c = i * 256 + tid;
      int kd = c >> 8, t = (c >> 2) & 63, cc = (c & 3) ^ ((c >> 3) & 3);
      gl_lds16(kb + (size_t)(tbase + tc + t) * DK + kd * 32 + cc * 8, &Ks2[(i * 256 + w * 64) * 8]);
    }
  };
  auto stageV = [&](int buf, int tc) {
#pragma unroll
    for (int i = 0; i < 4; i++) {
      int c = i * 256 + tid;
      int kt = c >> 9, d = (c >> 2) & 127, cc = (c & 3) ^ ((c >> 3) & 3);
      gl_lds16(vT + (size_t)d * SEQ + tbase + tc + kt * 32 + cc * 8, &Vs2[buf][(i * 256 + w * 64) * 8]);
    }
  };

  bf16x8 qf[2][4];                                  // wave's q strip, loop-invariant
#pragma unroll
  for (int ni = 0; ni < 2; ni++)
#pragma unroll
    for (int kd = 0; kd < 4; kd++)
      qf[ni][kd] = *(const bf16x8*)(qb + (size_t)(s0 + w * 32 + ni * 16 + r15) * DK + kd * 32 + gq * 8);

  stageK(0);
  stageV(0, 0);
  asm volatile("s_waitcnt vmcnt(0)" ::: "memory");
  __syncthreads();

  f32x4 o[4][4] = {};
  for (int tc = 0; tc < 1024; tc += 64) {
    int vbuf = (tc >> 6) & 1;
    // prefetch mL window for this chunk (L2-resident)
    float4 mv4[4];
#pragma unroll
    for (int mi = 0; mi < 4; mi++)
      mv4[mi] = *(const float4*)(mLg + tbase + tc + mi * 16 + gq * 4);
    // QK (swapped: P^T[t][s]) + exp + pack to Ps
#pragma unroll
    for (int mi = 0; mi < 4; mi++) {
      bf16x8 a4[4];
#pragma unroll
      for (int kd = 0; kd < 4; kd++)
        a4[kd] = *(const bf16x8*)&Ks2[kd * 2048 + (mi * 16 + r15) * 32 + gqx * 8];
      f32x4 p0 = {}, p1 = {};
#pragma unroll
      for (int kd = 0; kd < 4; kd++) {
        p0 = mfma16(a4[kd], qf[0][kd], p0);
        p1 = mfma16(a4[kd], qf[1][kd], p1);
      }
      ushort4 pk0, pk1;
      {
        float e;
        float mv0 = mv4[mi].x, mv1 = mv4[mi].y, mv2 = mv4[mi].z, mv3 = mv4[mi].w;
        e = __builtin_amdgcn_exp2f(fmaf(p0[0], L2E, -mv0)); pk0.x = f2bf_fast(e);
        e = __builtin_amdgcn_exp2f(fmaf(p0[1], L2E, -mv1)); pk0.y = f2bf_fast(e);
        e = __builtin_amdgcn_exp2f(fmaf(p0[2], L2E, -mv2)); pk0.z = f2bf_fast(e);
        e = __builtin_amdgcn_exp2f(fmaf(p0[3], L2E, -mv3)); pk0.w = f2bf_fast(e);
        e = __builtin_amdgcn_exp2f(fmaf(p1[0], L2E, -mv0)); pk1.x = f2bf_fast(e);
        e = __builtin_amdgcn_exp2f(fmaf(p1[1], L2E, -mv1)); pk1.y = f2bf_fast(e);
        e = __builtin_amdgcn_exp2f(fmaf(p1[2], L2E, -mv2)); pk1.z = f2bf_fast(e);
        e = __builtin_amdgcn_exp2f(fmaf(p1[3], L2E, -mv3)); pk1.w = f2bf_fast(e);
      }
      int ktp = mi >> 1;
      int w32 = (mi & 1) * 16 + gq * 4;
      *(ushort4*)&Ps[ktp * 5120 + (w * 32 + r15) * 40 + w32] = pk0;
      *(ushort4*)&Ps[ktp * 5120 + (w * 32 + 16 + r15) * 40 + w32] = pk1;
    }
    __syncthreads();   // B1: QK done -> Ks2 dead, Ps ready
    if (tc < 960) {    // stage next K/V; latency hides under PV
      stageK(tc + 64);
      stageV(vbuf ^ 1, tc + 64);
    }
    // PV
    __builtin_amdgcn_s_setprio(1);
#pragma unroll
    for (int kt = 0; kt < 2; kt++) {
      bf16x8 pa[4], vv[4];
#pragma unroll
      for (int mi2 = 0; mi2 < 4; mi2++)
        pa[mi2] = *(const bf16x8*)&Ps[kt * 5120 + (wr * 64 + mi2 * 16 + r15) * 40 + gq * 8];
#pragma unroll
      for (int ni2 = 0; ni2 < 4; ni2++)
        vv[ni2] = *(const bf16x8*)&Vs2[vbuf][kt * 4096 + (wc * 64 + ni2 * 16 + r15) * 32 + gqx * 8];
#pragma unroll
      for (int mi2 = 0; mi2 < 4; mi2++)
#pragma unroll
        for (int ni2 = 0; ni2 < 4; ni2++)
          o[mi2][ni2] = mfma16(pa[mi2], vv[ni2], o[mi2][ni2]);
    }
    __builtin_amdgcn_s_setprio(0);
    asm volatile("s_waitcnt vmcnt(0)" ::: "memory");
    __syncthreads();   // B2: PV done, next K/V landed
  }
  float* dst = outp + (size_t)ts * SEQ * DK;
#pragma unroll
  for (int mi2 = 0; mi2 < 4; mi2++)
#pragma unroll
    for (int ni2 = 0; ni2 < 4; ni2++)
#pragma unroll
      for (int rr = 0; rr < 4; rr++) {
        int srow = s0 + wr * 64 + mi2 * 16 + gq * 4 + rr;
        int dcol = wc * 64 + ni2 * 16 + r15;
        dst[(size_t)srow * DK + dcol] = o[mi2][ni2][rr];
      }
}

// ---------------- P4: reduce 8 t-split partials ----------------
__global__ __launch_bounds__(256) void k_p4(const float* __restrict__ outp, float* __restrict__ out) {
  int i = blockIdx.x * 256 + threadIdx.x;   // grid 1024, float4 each
  const float4* s = (const float4*)outp;
  float4 a = s[i];
#pragma unroll
  for (int p = 1; p < 8; p++) {
    float4 b = s[(size_t)p * 262144 + i];
    a.x += b.x; a.y += b.y; a.z += b.z; a.w += b.w;
  }
  ((float4*)out)[i] = a;
}

extern "C" void kernel_launch(void* const* d_in, const int* in_sizes, int n_in,
                              void* d_out, int out_size, void* d_ws, size_t ws_size,
                              hipStream_t stream) {
  (void)in_sizes; (void)n_in; (void)out_size; (void)ws_size;
  const float* x  = (const float*)d_in[0];
  const float* wq = (const float*)d_in[1];
  const float* wk = (const float*)d_in[2];
  const float* wv = (const float*)d_in[3];
  float* out = (float*)d_out;

  char* wsb = (char*)d_ws;
  float* outp  = (float*)wsb;                     // 32 MB
  u16*   wT    = (u16*)(wsb + 33554432);          // 1.5 MB
  u16*   qb    = (u16*)(wsb + 35127296);          // 2 MB (prescaled by sqrt(dk))
  u16*   kb    = (u16*)(wsb + 37224448);          // 2 MB
  u16*   vb    = (u16*)(wsb + 39321600);          // 2 MB
  u16*   vT    = (u16*)(wsb + 41418752);          // 2 MB  (v/Z, transposed [d][t])
  float* mLf   = (float*)(wsb + 43515904);        // 32 KB (max in log2-space)
  float* mpart = (float*)(wsb + 43548672);        // 256 KB
  float* zpart = (float*)(wsb + 43810816);        // 256 KB

  k_cvt_w<<<dim3(256, 3), 256, 0, stream>>>(wq, wk, wv, wT);
  k_qkv<<<384, 256, 0, stream>>>(x, wT, qb, kb, vb);
  k_p2<<<512, 256, 0, stream>>>(qb, kb, mpart, zpart);
  k_p2c<<<128, 256, 0, stream>>>(mpart, zpart, vb, mLf, vT);
  k_p3<<<512, 256, 0, stream>>>(qb, kb, vT, mLf, outp);
  k_p4<<<1024, 256, 0, stream>>>(outp, out);
}